// Round 1
// baseline (2117.161 us; speedup 1.0000x reference)
//
#include <hip/hip_runtime.h>
#include <hip/hip_bf16.h>

// Problem: S=2048, D_MODEL=2048, H=16, HD=128
// out = softmax1((q@Wq^T)(k@Wk^T)^T / sqrt(HD)) @ (v@Wv^T) * scalars @ Wo^T
//
// Round 1: fp32 correctness baseline.
//  - gemm_nt_2048: C = A @ B^T, 2048^3, 64x64 tile, BK=16, 4x4 microtile/thread
//  - attn_flash: per (32-q-rows, head) block, online softmax1 (init m=0,l=1
//    absorbs the off-by-one '+exp(-m)' term as a phantom key)
//  - attn result aliases qh in workspace (block reads its q slice into LDS
//    before writing the identical region; disjoint across blocks).

#define S_LEN 2048
#define DMODEL 2048
#define NHEAD 16
#define HEADD 128

__global__ __launch_bounds__(256) void gemm_nt_2048(const float* __restrict__ A,
                                                    const float* __restrict__ B,
                                                    float* __restrict__ C) {
    constexpr int K = DMODEL, N = DMODEL, BK = 16;
    __shared__ __align__(16) float As[BK][64 + 4];
    __shared__ __align__(16) float Bs[BK][64 + 4];
    const int tid = threadIdx.x;
    const int tn = tid & 15;       // 0..15 -> 4 cols each
    const int tm = tid >> 4;       // 0..15 -> 4 rows each
    const size_t row0 = (size_t)blockIdx.y * 64;
    const size_t col0 = (size_t)blockIdx.x * 64;
    const float* Ab = A + row0 * K;
    const float* Bb = B + col0 * K;

    float acc[4][4] = {};
    const int lr = tid >> 2;          // 0..63 row within tile
    const int lk = (tid & 3) * 4;     // 0,4,8,12 k-offset

    for (int k0 = 0; k0 < K; k0 += BK) {
        float4 av = *(const float4*)&Ab[(size_t)lr * K + k0 + lk];
        float4 bv = *(const float4*)&Bb[(size_t)lr * K + k0 + lk];
        As[lk + 0][lr] = av.x; As[lk + 1][lr] = av.y;
        As[lk + 2][lr] = av.z; As[lk + 3][lr] = av.w;
        Bs[lk + 0][lr] = bv.x; Bs[lk + 1][lr] = bv.y;
        Bs[lk + 2][lr] = bv.z; Bs[lk + 3][lr] = bv.w;
        __syncthreads();
#pragma unroll
        for (int kk = 0; kk < BK; ++kk) {
            float4 a = *(const float4*)&As[kk][tm * 4];
            float4 b = *(const float4*)&Bs[kk][tn * 4];
            float ar[4] = {a.x, a.y, a.z, a.w};
            float br[4] = {b.x, b.y, b.z, b.w};
#pragma unroll
            for (int i = 0; i < 4; ++i)
#pragma unroll
                for (int j = 0; j < 4; ++j)
                    acc[i][j] += ar[i] * br[j];
        }
        __syncthreads();
    }
#pragma unroll
    for (int i = 0; i < 4; ++i) {
        float4 v = make_float4(acc[i][0], acc[i][1], acc[i][2], acc[i][3]);
        *(float4*)&C[(row0 + tm * 4 + i) * N + col0 + tn * 4] = v;
    }
}

// One block: 32 q-rows x 1 head. 256 threads.
__global__ __launch_bounds__(256) void attn_flash(const float* __restrict__ qh,
                                                  const float* __restrict__ kh,
                                                  const float* __restrict__ vh,
                                                  const float* __restrict__ scalars,
                                                  float* __restrict__ attn_out) {
    const int h = blockIdx.y;
    const int q0 = blockIdx.x * 32;
    __shared__ __align__(16) float qs[32][132];
    __shared__ __align__(16) float ks[32][132];
    __shared__ __align__(16) float vs[32][132];
    __shared__ float ps[32][33];
    __shared__ float m_s[32], l_s[32], alpha_s[32];

    const int tid = threadIdx.x;
    const float scale = 0.08838834764831844f;  // 1/sqrt(128)

    // load + pre-scale q tile (32x128) as float4
#pragma unroll
    for (int i = 0; i < 4; ++i) {
        int f4 = tid + i * 256;          // 0..1023
        int r = f4 >> 5, c4 = (f4 & 31) * 4;
        float4 v = *(const float4*)&qh[(size_t)(q0 + r) * DMODEL + h * HEADD + c4];
        v.x *= scale; v.y *= scale; v.z *= scale; v.w *= scale;
        *(float4*)&qs[r][c4] = v;
    }
    if (tid < 32) { m_s[tid] = 0.f; l_s[tid] = 1.f; }

    float acc[16];
#pragma unroll
    for (int j = 0; j < 16; ++j) acc[j] = 0.f;

    const int r_own = tid >> 3;   // 0..31: accumulator row
    const int d0 = tid & 7;       // dims d0*16 .. d0*16+15
    const int rg = tid >> 4;      // q rows 2rg, 2rg+1
    const int cg = tid & 15;      // k rows 2cg, 2cg+1
    __syncthreads();

    for (int k0 = 0; k0 < S_LEN; k0 += 32) {
#pragma unroll
        for (int i = 0; i < 4; ++i) {
            int f4 = tid + i * 256;
            int r = f4 >> 5, c4 = (f4 & 31) * 4;
            *(float4*)&ks[r][c4] =
                *(const float4*)&kh[(size_t)(k0 + r) * DMODEL + h * HEADD + c4];
            *(float4*)&vs[r][c4] =
                *(const float4*)&vh[(size_t)(k0 + r) * DMODEL + h * HEADD + c4];
        }
        __syncthreads();

        // s = q_tile @ k_tile^T : 2x2 per thread
        float s00 = 0.f, s01 = 0.f, s10 = 0.f, s11 = 0.f;
        const float4* q0p = (const float4*)&qs[2 * rg][0];
        const float4* q1p = (const float4*)&qs[2 * rg + 1][0];
        const float4* k0p = (const float4*)&ks[2 * cg][0];
        const float4* k1p = (const float4*)&ks[2 * cg + 1][0];
#pragma unroll
        for (int dd = 0; dd < 32; ++dd) {
            float4 a0 = q0p[dd], a1 = q1p[dd], b0 = k0p[dd], b1 = k1p[dd];
            s00 += a0.x * b0.x + a0.y * b0.y + a0.z * b0.z + a0.w * b0.w;
            s01 += a0.x * b1.x + a0.y * b1.y + a0.z * b1.z + a0.w * b1.w;
            s10 += a1.x * b0.x + a1.y * b0.y + a1.z * b0.z + a1.w * b0.w;
            s11 += a1.x * b1.x + a1.y * b1.y + a1.z * b1.z + a1.w * b1.w;
        }
        ps[2 * rg][2 * cg] = s00;
        ps[2 * rg][2 * cg + 1] = s01;
        ps[2 * rg + 1][2 * cg] = s10;
        ps[2 * rg + 1][2 * cg + 1] = s11;
        __syncthreads();

        // online softmax1 update (one thread per row)
        if (tid < 32) {
            float mx = m_s[tid];
            float t = ps[tid][0];
#pragma unroll
            for (int c = 1; c < 32; ++c) t = fmaxf(t, ps[tid][c]);
            float m_new = fmaxf(mx, t);
            float alpha = __expf(mx - m_new);
            float sum = 0.f;
#pragma unroll
            for (int c = 0; c < 32; ++c) {
                float e = __expf(ps[tid][c] - m_new);
                ps[tid][c] = e;
                sum += e;
            }
            l_s[tid] = l_s[tid] * alpha + sum;
            m_s[tid] = m_new;
            alpha_s[tid] = alpha;
        }
        __syncthreads();

        float al = alpha_s[r_own];
#pragma unroll
        for (int j = 0; j < 16; ++j) acc[j] *= al;
#pragma unroll
        for (int c = 0; c < 32; ++c) {
            float p = ps[r_own][c];
            const float* vrow = &vs[c][d0 * 16];
#pragma unroll
            for (int j = 0; j < 16; ++j) acc[j] += p * vrow[j];
        }
        __syncthreads();
    }

    const float wmul = scalars[h] / l_s[r_own];
#pragma unroll
    for (int u = 0; u < 4; ++u) {
        float4 v = make_float4(acc[u * 4 + 0] * wmul, acc[u * 4 + 1] * wmul,
                               acc[u * 4 + 2] * wmul, acc[u * 4 + 3] * wmul);
        *(float4*)&attn_out[(size_t)(q0 + r_own) * DMODEL + h * HEADD + d0 * 16 + u * 4] = v;
    }
}

extern "C" void kernel_launch(void* const* d_in, const int* in_sizes, int n_in,
                              void* d_out, int out_size, void* d_ws, size_t ws_size,
                              hipStream_t stream) {
    const float* query   = (const float*)d_in[0];
    const float* key_    = (const float*)d_in[1];
    const float* value   = (const float*)d_in[2];
    const float* Wq      = (const float*)d_in[3];
    const float* Wk      = (const float*)d_in[4];
    const float* Wv      = (const float*)d_in[5];
    const float* Wo      = (const float*)d_in[6];
    const float* scalars = (const float*)d_in[7];
    float* out = (float*)d_out;

    float* qh = (float*)d_ws;                       // 16 MB
    float* kh = qh + (size_t)S_LEN * DMODEL;        // 16 MB
    float* vh = kh + (size_t)S_LEN * DMODEL;        // 16 MB

    dim3 gg(DMODEL / 64, S_LEN / 64), gb(256);
    gemm_nt_2048<<<gg, gb, 0, stream>>>(query, Wq, qh);
    gemm_nt_2048<<<gg, gb, 0, stream>>>(key_,  Wk, kh);
    gemm_nt_2048<<<gg, gb, 0, stream>>>(value, Wv, vh);

    // attention: writes aliased onto qh (disjoint per-block read-then-write)
    attn_flash<<<dim3(S_LEN / 32, NHEAD), 256, 0, stream>>>(qh, kh, vh, scalars, qh);

    gemm_nt_2048<<<gg, gb, 0, stream>>>(qh, Wo, out);
}

// Round 3
// 1374.576 us; speedup vs baseline: 1.5402x; 1.5402x over previous
//
#include <hip/hip_runtime.h>
#include <hip/hip_bf16.h>

// Problem: S=2048, D_MODEL=2048, H=16, HD=128
// out = softmax1((q@Wq^T)(k@Wk^T)^T / sqrt(HD)) @ (v@Wv^T) * scalars @ Wo^T
//
// Round 3 (= round-2 with compile fix):
//  - gemm_nt_split: C = A @ B^T via split-bf16 MFMA emulation of fp32:
//      a = a_hi + a_lo (bf16 each), product = hi*hi + hi*lo + lo*hi (lo*lo
//      dropped, ~2^-17 rel err). 128x128 tile, BK=32, 16x16x32 bf16 MFMA,
//      4 waves each computing 64x64 (4x4 fragment grid).
//  - attn_flash: fp32, bank-conflict fixes: S rows (x, x+16) pairing; PV dims
//      owned as u*32 + d0*4 (float4 spans all 32 banks exactly once).

#define S_LEN 2048
#define DMODEL 2048
#define NHEAD 16
#define HEADD 128

typedef __bf16 bf16x8 __attribute__((ext_vector_type(8)));
typedef __bf16 bf16x4 __attribute__((ext_vector_type(4)));
typedef float f32x4 __attribute__((ext_vector_type(4)));

#define PADK 40  // 32 + 8 pad elems -> 80B row stride (8B aligned, 2-way max)

__device__ inline __bf16 bf_hi(float x) { return (__bf16)x; }
__device__ inline __bf16 bf_lo(float x, __bf16 h) { return (__bf16)(x - (float)h); }

__global__ __launch_bounds__(256) void gemm_nt_split(const float* __restrict__ A,
                                                     const float* __restrict__ B,
                                                     float* __restrict__ C) {
    constexpr int K = DMODEL, N = DMODEL, BK = 32;
    __shared__ __align__(16) __bf16 Ahi[128][PADK];
    __shared__ __align__(16) __bf16 Alo[128][PADK];
    __shared__ __align__(16) __bf16 Bhi[128][PADK];
    __shared__ __align__(16) __bf16 Blo[128][PADK];

    const int tid = threadIdx.x;
    const int lane = tid & 63;
    const int wave = tid >> 6;
    const int wm = (wave >> 1) * 64;   // wave's 64x64 sub-tile origin
    const int wn = (wave & 1) * 64;
    const int lr = lane & 15;          // fragment row (m for A, n for B)
    const int lk = (lane >> 4) * 8;    // fragment k offset (8 contiguous)
    const size_t row0 = (size_t)blockIdx.y * 128;
    const size_t col0 = (size_t)blockIdx.x * 128;

    f32x4 acc[4][4] = {};

    for (int k0 = 0; k0 < K; k0 += BK) {
        // ---- stage 128x32 fp32 tiles of A and B, converting to hi/lo bf16
#pragma unroll
        for (int i = 0; i < 4; ++i) {
            int idx = tid + i * 256;          // 0..1023
            int r = idx >> 3;                 // 0..127
            int c4 = (idx & 7) * 4;           // 0,4,...,28
            float4 av = *(const float4*)&A[(row0 + r) * K + k0 + c4];
            float4 bv = *(const float4*)&B[(col0 + r) * K + k0 + c4];
            bf16x4 ah, al, bh, bl;
            {
                __bf16 h0 = bf_hi(av.x), h1 = bf_hi(av.y), h2 = bf_hi(av.z), h3 = bf_hi(av.w);
                ah[0] = h0; ah[1] = h1; ah[2] = h2; ah[3] = h3;
                al[0] = bf_lo(av.x, h0); al[1] = bf_lo(av.y, h1);
                al[2] = bf_lo(av.z, h2); al[3] = bf_lo(av.w, h3);
            }
            {
                __bf16 h0 = bf_hi(bv.x), h1 = bf_hi(bv.y), h2 = bf_hi(bv.z), h3 = bf_hi(bv.w);
                bh[0] = h0; bh[1] = h1; bh[2] = h2; bh[3] = h3;
                bl[0] = bf_lo(bv.x, h0); bl[1] = bf_lo(bv.y, h1);
                bl[2] = bf_lo(bv.z, h2); bl[3] = bf_lo(bv.w, h3);
            }
            *(bf16x4*)&Ahi[r][c4] = ah;
            *(bf16x4*)&Alo[r][c4] = al;
            *(bf16x4*)&Bhi[r][c4] = bh;
            *(bf16x4*)&Blo[r][c4] = bl;
        }
        __syncthreads();

        // ---- load fragments (two b64 reads each, 8B aligned)
        bf16x8 ah[4], al[4], bh[4], bl[4];
#pragma unroll
        for (int i = 0; i < 4; ++i) {
            bf16x4 a0 = *(const bf16x4*)&Ahi[wm + i * 16 + lr][lk];
            bf16x4 a1 = *(const bf16x4*)&Ahi[wm + i * 16 + lr][lk + 4];
            ah[i] = __builtin_shufflevector(a0, a1, 0, 1, 2, 3, 4, 5, 6, 7);
            bf16x4 a2 = *(const bf16x4*)&Alo[wm + i * 16 + lr][lk];
            bf16x4 a3 = *(const bf16x4*)&Alo[wm + i * 16 + lr][lk + 4];
            al[i] = __builtin_shufflevector(a2, a3, 0, 1, 2, 3, 4, 5, 6, 7);
            bf16x4 b0 = *(const bf16x4*)&Bhi[wn + i * 16 + lr][lk];
            bf16x4 b1 = *(const bf16x4*)&Bhi[wn + i * 16 + lr][lk + 4];
            bh[i] = __builtin_shufflevector(b0, b1, 0, 1, 2, 3, 4, 5, 6, 7);
            bf16x4 b2 = *(const bf16x4*)&Blo[wn + i * 16 + lr][lk];
            bf16x4 b3 = *(const bf16x4*)&Blo[wn + i * 16 + lr][lk + 4];
            bl[i] = __builtin_shufflevector(b2, b3, 0, 1, 2, 3, 4, 5, 6, 7);
        }

        // ---- 3-term split MFMA: hi*hi + hi*lo + lo*hi
#pragma unroll
        for (int i = 0; i < 4; ++i)
#pragma unroll
            for (int j = 0; j < 4; ++j) {
                acc[i][j] = __builtin_amdgcn_mfma_f32_16x16x32_bf16(ah[i], bh[j], acc[i][j], 0, 0, 0);
                acc[i][j] = __builtin_amdgcn_mfma_f32_16x16x32_bf16(ah[i], bl[j], acc[i][j], 0, 0, 0);
                acc[i][j] = __builtin_amdgcn_mfma_f32_16x16x32_bf16(al[i], bh[j], acc[i][j], 0, 0, 0);
            }
        __syncthreads();
    }

    // ---- epilogue: C/D layout col=lane&15, row=(lane>>4)*4+reg
    const int orow = (lane >> 4) * 4;
#pragma unroll
    for (int i = 0; i < 4; ++i)
#pragma unroll
        for (int j = 0; j < 4; ++j) {
#pragma unroll
            for (int r = 0; r < 4; ++r) {
                C[(row0 + wm + i * 16 + orow + r) * N + col0 + wn + j * 16 + lr] =
                    acc[i][j][r];
            }
        }
}

// One block: 32 q-rows x 1 head. 256 threads. fp32.
__global__ __launch_bounds__(256) void attn_flash(const float* __restrict__ qh,
                                                  const float* __restrict__ kh,
                                                  const float* __restrict__ vh,
                                                  const float* __restrict__ scalars,
                                                  float* __restrict__ attn_out) {
    const int h = blockIdx.y;
    const int q0 = blockIdx.x * 32;
    __shared__ __align__(16) float qs[32][132];
    __shared__ __align__(16) float ks[32][132];
    __shared__ __align__(16) float vs[32][132];
    __shared__ float ps[32][33];
    __shared__ float m_s[32], l_s[32], alpha_s[32];

    const int tid = threadIdx.x;
    const float scale = 0.08838834764831844f;  // 1/sqrt(128)

    // load + pre-scale q tile (32x128) as float4
#pragma unroll
    for (int i = 0; i < 4; ++i) {
        int f4 = tid + i * 256;          // 0..1023
        int r = f4 >> 5, c4 = (f4 & 31) * 4;
        float4 v = *(const float4*)&qh[(size_t)(q0 + r) * DMODEL + h * HEADD + c4];
        v.x *= scale; v.y *= scale; v.z *= scale; v.w *= scale;
        *(float4*)&qs[r][c4] = v;
    }
    if (tid < 32) { m_s[tid] = 0.f; l_s[tid] = 1.f; }

    float acc[16];
#pragma unroll
    for (int j = 0; j < 16; ++j) acc[j] = 0.f;

    const int r_own = tid >> 3;   // 0..31: accumulator row
    const int d0 = tid & 7;       // dims u*32 + d0*4 + (0..3), u=0..3
    const int rg = tid >> 4;      // q rows rg, rg+16
    const int cg = tid & 15;      // k rows cg, cg+16
    __syncthreads();

    for (int k0 = 0; k0 < S_LEN; k0 += 32) {
#pragma unroll
        for (int i = 0; i < 4; ++i) {
            int f4 = tid + i * 256;
            int r = f4 >> 5, c4 = (f4 & 31) * 4;
            *(float4*)&ks[r][c4] =
                *(const float4*)&kh[(size_t)(k0 + r) * DMODEL + h * HEADD + c4];
            *(float4*)&vs[r][c4] =
                *(const float4*)&vh[(size_t)(k0 + r) * DMODEL + h * HEADD + c4];
        }
        __syncthreads();

        // s = q_tile @ k_tile^T : rows (rg, rg+16) x cols (cg, cg+16)
        float s00 = 0.f, s01 = 0.f, s10 = 0.f, s11 = 0.f;
        const float4* q0p = (const float4*)&qs[rg][0];
        const float4* q1p = (const float4*)&qs[rg + 16][0];
        const float4* k0p = (const float4*)&ks[cg][0];
        const float4* k1p = (const float4*)&ks[cg + 16][0];
#pragma unroll
        for (int dd = 0; dd < 32; ++dd) {
            float4 a0 = q0p[dd], a1 = q1p[dd], b0 = k0p[dd], b1 = k1p[dd];
            s00 += a0.x * b0.x + a0.y * b0.y + a0.z * b0.z + a0.w * b0.w;
            s01 += a0.x * b1.x + a0.y * b1.y + a0.z * b1.z + a0.w * b1.w;
            s10 += a1.x * b0.x + a1.y * b0.y + a1.z * b0.z + a1.w * b0.w;
            s11 += a1.x * b1.x + a1.y * b1.y + a1.z * b1.z + a1.w * b1.w;
        }
        ps[rg][cg] = s00;
        ps[rg][cg + 16] = s01;
        ps[rg + 16][cg] = s10;
        ps[rg + 16][cg + 16] = s11;
        __syncthreads();

        // online softmax1 update (one thread per row; init m=0,l=1 absorbs +exp(-m))
        if (tid < 32) {
            float mx = m_s[tid];
            float t = ps[tid][0];
#pragma unroll
            for (int c = 1; c < 32; ++c) t = fmaxf(t, ps[tid][c]);
            float m_new = fmaxf(mx, t);
            float alpha = __expf(mx - m_new);
            float sum = 0.f;
#pragma unroll
            for (int c = 0; c < 32; ++c) {
                float e = __expf(ps[tid][c] - m_new);
                ps[tid][c] = e;
                sum += e;
            }
            l_s[tid] = l_s[tid] * alpha + sum;
            m_s[tid] = m_new;
            alpha_s[tid] = alpha;
        }
        __syncthreads();

        float al = alpha_s[r_own];
#pragma unroll
        for (int j = 0; j < 16; ++j) acc[j] *= al;
#pragma unroll
        for (int c = 0; c < 32; ++c) {
            float p = ps[r_own][c];
#pragma unroll
            for (int u = 0; u < 4; ++u) {
                float4 v = *(const float4*)&vs[c][u * 32 + d0 * 4];
                acc[u * 4 + 0] += p * v.x;
                acc[u * 4 + 1] += p * v.y;
                acc[u * 4 + 2] += p * v.z;
                acc[u * 4 + 3] += p * v.w;
            }
        }
        __syncthreads();
    }

    const float wmul = scalars[h] / l_s[r_own];
#pragma unroll
    for (int u = 0; u < 4; ++u) {
        float4 v = make_float4(acc[u * 4 + 0] * wmul, acc[u * 4 + 1] * wmul,
                               acc[u * 4 + 2] * wmul, acc[u * 4 + 3] * wmul);
        *(float4*)&attn_out[(size_t)(q0 + r_own) * DMODEL + h * HEADD + u * 32 + d0 * 4] = v;
    }
}

extern "C" void kernel_launch(void* const* d_in, const int* in_sizes, int n_in,
                              void* d_out, int out_size, void* d_ws, size_t ws_size,
                              hipStream_t stream) {
    const float* query   = (const float*)d_in[0];
    const float* key_    = (const float*)d_in[1];
    const float* value   = (const float*)d_in[2];
    const float* Wq      = (const float*)d_in[3];
    const float* Wk      = (const float*)d_in[4];
    const float* Wv      = (const float*)d_in[5];
    const float* Wo      = (const float*)d_in[6];
    const float* scalars = (const float*)d_in[7];
    float* out = (float*)d_out;

    float* qh = (float*)d_ws;                       // 16 MB
    float* kh = qh + (size_t)S_LEN * DMODEL;        // 16 MB
    float* vh = kh + (size_t)S_LEN * DMODEL;        // 16 MB

    dim3 gg(DMODEL / 128, S_LEN / 128), gb(256);
    gemm_nt_split<<<gg, gb, 0, stream>>>(query, Wq, qh);
    gemm_nt_split<<<gg, gb, 0, stream>>>(key_,  Wk, kh);
    gemm_nt_split<<<gg, gb, 0, stream>>>(value, Wv, vh);

    // attention: writes aliased onto qh (disjoint per-block read-then-write)
    attn_flash<<<dim3(S_LEN / 32, NHEAD), 256, 0, stream>>>(qh, kh, vh, scalars, qh);

    gemm_nt_split<<<gg, gb, 0, stream>>>(qh, Wo, out);
}

// Round 4
// 711.680 us; speedup vs baseline: 2.9749x; 1.9315x over previous
//
#include <hip/hip_runtime.h>
#include <hip/hip_bf16.h>

// Problem: S=2048, D_MODEL=2048, H=16, HD=128
// out = softmax1((q@Wq^T)(k@Wk^T)^T / sqrt(HD)) @ (v@Wv^T) * scalars @ Wo^T
//
// Round 4:
//  - gemm_nt_split<TOUT>: C = A @ B^T via split-bf16 MFMA (hi*hi+hi*lo+lo*hi).
//    TOUT=float for qh/kh/out, TOUT=bf16 for vhT (V transposed by operand swap:
//    gemm(Wv, value) = vh^T, k-contiguous for the PV MFMA B-operand).
//  - attn_mfma: MFMA flash attention, 64 q-rows x 1 head per block, K-tile 64.
//    QK^T split-bf16 3-term; P,V plain bf16; softmax1 via m=0,l=1 init.
//    Softmax state in registers (C/D row mapping consistent across QK and PV).

#define S_LEN 2048
#define DMODEL 2048
#define NHEAD 16
#define HEADD 128

typedef __bf16 bf16x8 __attribute__((ext_vector_type(8)));
typedef __bf16 bf16x4 __attribute__((ext_vector_type(4)));
typedef float f32x4 __attribute__((ext_vector_type(4)));

#define PADK 40  // GEMM LDS row stride (32 + 8)

__device__ inline __bf16 bf_hi(float x) { return (__bf16)x; }
__device__ inline __bf16 bf_lo(float x, __bf16 h) { return (__bf16)(x - (float)h); }

template <typename TOUT>
__device__ inline TOUT to_out(float x);
template <>
__device__ inline float to_out<float>(float x) { return x; }
template <>
__device__ inline __hip_bfloat16 to_out<__hip_bfloat16>(float x) { return __float2bfloat16(x); }

template <typename TOUT>
__global__ __launch_bounds__(256) void gemm_nt_split(const float* __restrict__ A,
                                                     const float* __restrict__ B,
                                                     TOUT* __restrict__ C) {
    constexpr int K = DMODEL, N = DMODEL, BK = 32;
    __shared__ __align__(16) __bf16 Ahi[128][PADK];
    __shared__ __align__(16) __bf16 Alo[128][PADK];
    __shared__ __align__(16) __bf16 Bhi[128][PADK];
    __shared__ __align__(16) __bf16 Blo[128][PADK];

    const int tid = threadIdx.x;
    const int lane = tid & 63;
    const int wave = tid >> 6;
    const int wm = (wave >> 1) * 64;
    const int wn = (wave & 1) * 64;
    const int lr = lane & 15;
    const int lk = (lane >> 4) * 8;
    const size_t row0 = (size_t)blockIdx.y * 128;
    const size_t col0 = (size_t)blockIdx.x * 128;

    f32x4 acc[4][4] = {};

    for (int k0 = 0; k0 < K; k0 += BK) {
#pragma unroll
        for (int i = 0; i < 4; ++i) {
            int idx = tid + i * 256;
            int r = idx >> 3;
            int c4 = (idx & 7) * 4;
            float4 av = *(const float4*)&A[(row0 + r) * K + k0 + c4];
            float4 bv = *(const float4*)&B[(col0 + r) * K + k0 + c4];
            bf16x4 ah, al, bh, bl;
            {
                __bf16 h0 = bf_hi(av.x), h1 = bf_hi(av.y), h2 = bf_hi(av.z), h3 = bf_hi(av.w);
                ah[0] = h0; ah[1] = h1; ah[2] = h2; ah[3] = h3;
                al[0] = bf_lo(av.x, h0); al[1] = bf_lo(av.y, h1);
                al[2] = bf_lo(av.z, h2); al[3] = bf_lo(av.w, h3);
            }
            {
                __bf16 h0 = bf_hi(bv.x), h1 = bf_hi(bv.y), h2 = bf_hi(bv.z), h3 = bf_hi(bv.w);
                bh[0] = h0; bh[1] = h1; bh[2] = h2; bh[3] = h3;
                bl[0] = bf_lo(bv.x, h0); bl[1] = bf_lo(bv.y, h1);
                bl[2] = bf_lo(bv.z, h2); bl[3] = bf_lo(bv.w, h3);
            }
            *(bf16x4*)&Ahi[r][c4] = ah;
            *(bf16x4*)&Alo[r][c4] = al;
            *(bf16x4*)&Bhi[r][c4] = bh;
            *(bf16x4*)&Blo[r][c4] = bl;
        }
        __syncthreads();

        bf16x8 ah[4], al[4], bh[4], bl[4];
#pragma unroll
        for (int i = 0; i < 4; ++i) {
            bf16x4 a0 = *(const bf16x4*)&Ahi[wm + i * 16 + lr][lk];
            bf16x4 a1 = *(const bf16x4*)&Ahi[wm + i * 16 + lr][lk + 4];
            ah[i] = __builtin_shufflevector(a0, a1, 0, 1, 2, 3, 4, 5, 6, 7);
            bf16x4 a2 = *(const bf16x4*)&Alo[wm + i * 16 + lr][lk];
            bf16x4 a3 = *(const bf16x4*)&Alo[wm + i * 16 + lr][lk + 4];
            al[i] = __builtin_shufflevector(a2, a3, 0, 1, 2, 3, 4, 5, 6, 7);
            bf16x4 b0 = *(const bf16x4*)&Bhi[wn + i * 16 + lr][lk];
            bf16x4 b1 = *(const bf16x4*)&Bhi[wn + i * 16 + lr][lk + 4];
            bh[i] = __builtin_shufflevector(b0, b1, 0, 1, 2, 3, 4, 5, 6, 7);
            bf16x4 b2 = *(const bf16x4*)&Blo[wn + i * 16 + lr][lk];
            bf16x4 b3 = *(const bf16x4*)&Blo[wn + i * 16 + lr][lk + 4];
            bl[i] = __builtin_shufflevector(b2, b3, 0, 1, 2, 3, 4, 5, 6, 7);
        }

#pragma unroll
        for (int i = 0; i < 4; ++i)
#pragma unroll
            for (int j = 0; j < 4; ++j) {
                acc[i][j] = __builtin_amdgcn_mfma_f32_16x16x32_bf16(ah[i], bh[j], acc[i][j], 0, 0, 0);
                acc[i][j] = __builtin_amdgcn_mfma_f32_16x16x32_bf16(ah[i], bl[j], acc[i][j], 0, 0, 0);
                acc[i][j] = __builtin_amdgcn_mfma_f32_16x16x32_bf16(al[i], bh[j], acc[i][j], 0, 0, 0);
            }
        __syncthreads();
    }

    const int orow = (lane >> 4) * 4;
#pragma unroll
    for (int i = 0; i < 4; ++i)
#pragma unroll
        for (int j = 0; j < 4; ++j)
#pragma unroll
            for (int r = 0; r < 4; ++r)
                C[(row0 + wm + i * 16 + orow + r) * N + col0 + wn + j * 16 + lr] =
                    to_out<TOUT>(acc[i][j][r]);
}

// MFMA flash attention. Block = 64 q-rows x 1 head; 4 waves x 16 rows each.
__global__ __launch_bounds__(256) void attn_mfma(const float* __restrict__ qh,
                                                 const float* __restrict__ kh,
                                                 const __hip_bfloat16* __restrict__ vhT,
                                                 const float* __restrict__ scalars,
                                                 float* __restrict__ attn_out) {
    const int h = blockIdx.y;
    const int q0 = blockIdx.x * 64;
    __shared__ __align__(16) __bf16 Khi[64][136];  // [kpos][head-dim], 272B stride
    __shared__ __align__(16) __bf16 Klo[64][136];
    __shared__ __align__(16) __bf16 VT[128][72];   // [head-dim][kpos], 144B stride
    __shared__ __align__(16) __bf16 Ps[64][72];    // [q-row][kpos]

    const int tid = threadIdx.x;
    const int lane = tid & 63;
    const int wave = tid >> 6;
    const int qr = lane & 15;    // A row / B col within 16-tile
    const int quad = lane >> 4;  // k-segment selector; C/D row group
    const float scale = 0.08838834764831844f;  // 1/sqrt(128)

    // ---- Q fragments (rows q0 + wave*16 + qr), pre-scaled, split hi/lo
    bf16x8 qhi[4], qlo[4];
    {
        const float* qrow = qh + (size_t)(q0 + wave * 16 + qr) * DMODEL + h * HEADD;
#pragma unroll
        for (int kc = 0; kc < 4; ++kc) {
            float4 f0 = *(const float4*)&qrow[kc * 32 + quad * 8];
            float4 f1 = *(const float4*)&qrow[kc * 32 + quad * 8 + 4];
            float v[8] = {f0.x, f0.y, f0.z, f0.w, f1.x, f1.y, f1.z, f1.w};
            bf16x8 hv, lv;
#pragma unroll
            for (int j = 0; j < 8; ++j) {
                float x = v[j] * scale;
                __bf16 hh = (__bf16)x;
                hv[j] = hh;
                lv[j] = (__bf16)(x - (float)hh);
            }
            qhi[kc] = hv;
            qlo[kc] = lv;
        }
    }

    f32x4 oacc[8] = {};
    float m_r[4], l_r[4];
#pragma unroll
    for (int r = 0; r < 4; ++r) { m_r[r] = 0.f; l_r[r] = 1.f; }  // softmax1 init

    for (int k0 = 0; k0 < S_LEN; k0 += 64) {
        // ---- stage K tile (64 x 128 fp32 -> hi/lo bf16)
#pragma unroll
        for (int i = 0; i < 8; ++i) {
            int idx = tid + i * 256;
            int kp = idx >> 5;
            int c4 = (idx & 31) * 4;
            float4 f = *(const float4*)&kh[(size_t)(k0 + kp) * DMODEL + h * HEADD + c4];
            bf16x4 hv, lv;
            __bf16 h0 = bf_hi(f.x), h1 = bf_hi(f.y), h2 = bf_hi(f.z), h3 = bf_hi(f.w);
            hv[0] = h0; hv[1] = h1; hv[2] = h2; hv[3] = h3;
            lv[0] = bf_lo(f.x, h0); lv[1] = bf_lo(f.y, h1);
            lv[2] = bf_lo(f.z, h2); lv[3] = bf_lo(f.w, h3);
            *(bf16x4*)&Khi[kp][c4] = hv;
            *(bf16x4*)&Klo[kp][c4] = lv;
        }
        // ---- stage V^T tile (128 dims x 64 kpos, already bf16)
#pragma unroll
        for (int i = 0; i < 4; ++i) {
            int idx = tid + i * 256;
            int dm = idx >> 3;
            int c8 = (idx & 7) * 8;
            *(bf16x8*)&VT[dm][c8] =
                *(const bf16x8*)&vhT[(size_t)(h * HEADD + dm) * S_LEN + k0 + c8];
        }
        __syncthreads();

        // ---- S = Q K^T (split 3-term), 4 col-tiles of 16
        f32x4 S[4] = {};
#pragma unroll
        for (int jt = 0; jt < 4; ++jt) {
#pragma unroll
            for (int kc = 0; kc < 4; ++kc) {
                bf16x8 kh8 = *(const bf16x8*)&Khi[jt * 16 + qr][kc * 32 + quad * 8];
                bf16x8 kl8 = *(const bf16x8*)&Klo[jt * 16 + qr][kc * 32 + quad * 8];
                S[jt] = __builtin_amdgcn_mfma_f32_16x16x32_bf16(qhi[kc], kh8, S[jt], 0, 0, 0);
                S[jt] = __builtin_amdgcn_mfma_f32_16x16x32_bf16(qhi[kc], kl8, S[jt], 0, 0, 0);
                S[jt] = __builtin_amdgcn_mfma_f32_16x16x32_bf16(qlo[kc], kh8, S[jt], 0, 0, 0);
            }
        }

        // ---- online softmax1 per row (rows quad*4+r), P -> LDS bf16
#pragma unroll
        for (int r = 0; r < 4; ++r) {
            float mx = fmaxf(fmaxf(S[0][r], S[1][r]), fmaxf(S[2][r], S[3][r]));
#pragma unroll
            for (int m = 1; m < 16; m <<= 1) mx = fmaxf(mx, __shfl_xor(mx, m, 64));
            float m_new = fmaxf(m_r[r], mx);
            float alpha = __expf(m_r[r] - m_new);
            float sum = 0.f;
            int prow = wave * 16 + quad * 4 + r;
#pragma unroll
            for (int jt = 0; jt < 4; ++jt) {
                float e = __expf(S[jt][r] - m_new);
                sum += e;
                Ps[prow][jt * 16 + qr] = (__bf16)e;
            }
#pragma unroll
            for (int m = 1; m < 16; m <<= 1) sum += __shfl_xor(sum, m, 64);
            l_r[r] = l_r[r] * alpha + sum;
            m_r[r] = m_new;
#pragma unroll
            for (int nt = 0; nt < 8; ++nt) oacc[nt][r] *= alpha;
        }
        __syncthreads();

        // ---- O += P @ V  (P: A-operand from own rows; V^T: B-operand)
#pragma unroll
        for (int kc = 0; kc < 2; ++kc) {
            bf16x8 pf = *(const bf16x8*)&Ps[wave * 16 + qr][kc * 32 + quad * 8];
#pragma unroll
            for (int nt = 0; nt < 8; ++nt) {
                bf16x8 vf = *(const bf16x8*)&VT[nt * 16 + qr][kc * 32 + quad * 8];
                oacc[nt] = __builtin_amdgcn_mfma_f32_16x16x32_bf16(pf, vf, oacc[nt], 0, 0, 0);
            }
        }
        __syncthreads();
    }

    const float sh = scalars[h];
#pragma unroll
    for (int r = 0; r < 4; ++r) {
        float wm = sh / l_r[r];
        size_t rowoff = (size_t)(q0 + wave * 16 + quad * 4 + r) * DMODEL + h * HEADD;
#pragma unroll
        for (int nt = 0; nt < 8; ++nt)
            attn_out[rowoff + nt * 16 + qr] = oacc[nt][r] * wm;
    }
}

extern "C" void kernel_launch(void* const* d_in, const int* in_sizes, int n_in,
                              void* d_out, int out_size, void* d_ws, size_t ws_size,
                              hipStream_t stream) {
    const float* query   = (const float*)d_in[0];
    const float* key_    = (const float*)d_in[1];
    const float* value   = (const float*)d_in[2];
    const float* Wq      = (const float*)d_in[3];
    const float* Wk      = (const float*)d_in[4];
    const float* Wv      = (const float*)d_in[5];
    const float* Wo      = (const float*)d_in[6];
    const float* scalars = (const float*)d_in[7];
    float* out = (float*)d_out;

    float* qh = (float*)d_ws;                              // 16 MB
    float* kh = qh + (size_t)S_LEN * DMODEL;               // 16 MB
    __hip_bfloat16* vhT = (__hip_bfloat16*)(kh + (size_t)S_LEN * DMODEL);  // 8 MB

    dim3 gg(DMODEL / 128, S_LEN / 128), gb(256);
    gemm_nt_split<float><<<gg, gb, 0, stream>>>(query, Wq, qh);
    gemm_nt_split<float><<<gg, gb, 0, stream>>>(key_, Wk, kh);
    // operand swap: vhT = (value @ Wv^T)^T = Wv @ value^T, emitted bf16
    gemm_nt_split<__hip_bfloat16><<<gg, gb, 0, stream>>>(Wv, value, vhT);

    // attention writes onto qh (each block reads its Q slice first; disjoint)
    attn_mfma<<<dim3(S_LEN / 64, NHEAD), 256, 0, stream>>>(qh, kh, vhT, scalars, qh);

    gemm_nt_split<float><<<gg, gb, 0, stream>>>(qh, Wo, out);
}

// Round 5
// 574.091 us; speedup vs baseline: 3.6879x; 1.2397x over previous
//
#include <hip/hip_runtime.h>
#include <hip/hip_bf16.h>

// Problem: S=2048, D_MODEL=2048, H=16, HD=128
// out = softmax1((q@Wq^T)(k@Wk^T)^T / sqrt(HD)) @ (v@Wv^T) * scalars @ Wo^T
//
// Round 5:
//  - conv2: fp32 -> (hi,lo) bf16 planes, one-time split (scale folded into Wq).
//  - gemm_nt3: pure-bf16 3-term split GEMM (hi*hi+hi*lo+lo*hi), 128x64 tile
//    (512 blocks = 2/CU), BK=32, global_load_lds(16B) staging, zero staging VALU.
//  - attn_mfma: flash softmax1; K staged as bf16 hi/lo plane copies (padded LDS),
//    Q frags loaded bf16 directly; P,V plain bf16; output split to hi/lo planes
//    (aliased onto qh planes) feeding the Wo GEMM.

#define S_LEN 2048
#define DMODEL 2048
#define NHEAD 16
#define HEADD 128

typedef __bf16 bf16x8 __attribute__((ext_vector_type(8)));
typedef __bf16 bf16x4 __attribute__((ext_vector_type(4)));
typedef float f32x4 __attribute__((ext_vector_type(4)));

__device__ inline void async_copy16(const __bf16* g, __bf16* l) {
    __builtin_amdgcn_global_load_lds(
        (const __attribute__((address_space(1))) unsigned int*)g,
        (__attribute__((address_space(3))) unsigned int*)l, 16, 0, 0);
}

// ---- fp32 -> hi/lo bf16 split conversion, up to 2 matrices per launch ----
__global__ __launch_bounds__(256) void conv2(const float* __restrict__ s0,
                                             __hip_bfloat16* __restrict__ h0,
                                             __hip_bfloat16* __restrict__ l0,
                                             float sc0,
                                             const float* __restrict__ s1,
                                             __hip_bfloat16* __restrict__ h1,
                                             __hip_bfloat16* __restrict__ l1,
                                             float sc1) {
    const float* s = blockIdx.y ? s1 : s0;
    __hip_bfloat16* ph = blockIdx.y ? h1 : h0;
    __hip_bfloat16* pl = blockIdx.y ? l1 : l0;
    const float sc = blockIdx.y ? sc1 : sc0;
    size_t i4 = (size_t)blockIdx.x * 256 + threadIdx.x;  // float4 index
    float4 v = *(const float4*)&s[i4 * 4];
    float x0 = v.x * sc, x1 = v.y * sc, x2 = v.z * sc, x3 = v.w * sc;
    bf16x4 hv, lv;
    __bf16 a0 = (__bf16)x0, a1 = (__bf16)x1, a2 = (__bf16)x2, a3 = (__bf16)x3;
    hv[0] = a0; hv[1] = a1; hv[2] = a2; hv[3] = a3;
    lv[0] = (__bf16)(x0 - (float)a0); lv[1] = (__bf16)(x1 - (float)a1);
    lv[2] = (__bf16)(x2 - (float)a2); lv[3] = (__bf16)(x3 - (float)a3);
    *(bf16x4*)&ph[i4 * 4] = hv;
    *(bf16x4*)&pl[i4 * 4] = lv;
}

// ---- C = A @ B^T, A/B pre-split hi/lo bf16 planes. Tile 128(M) x 64(N), BK=32.
// OUTMODE: 0 = fp32, 1 = bf16, 2 = hi/lo bf16 planes
template <int OUTMODE>
__global__ __launch_bounds__(256) void gemm_nt3(const __bf16* __restrict__ Ahi,
                                                const __bf16* __restrict__ Alo,
                                                const __bf16* __restrict__ Bhi,
                                                const __bf16* __restrict__ Blo,
                                                float* __restrict__ Cf,
                                                __hip_bfloat16* __restrict__ Chi,
                                                __hip_bfloat16* __restrict__ Clo) {
    constexpr int K = DMODEL, N = DMODEL;
    __shared__ __bf16 sAhi[128 * 32], sAlo[128 * 32];
    __shared__ __bf16 sBhi[64 * 32], sBlo[64 * 32];

    const int tid = threadIdx.x;
    const int lane = tid & 63;
    const int wave = tid >> 6;
    const int qr = lane & 15;
    const int quad = lane >> 4;
    const int wm = (wave >> 1) * 64;   // wave sub-tile: 64 x 32
    const int wn = (wave & 1) * 32;
    const size_t row0 = (size_t)blockIdx.y * 128;
    const size_t col0 = (size_t)blockIdx.x * 64;

    // staging: chunk c -> row=c>>2, k8=(c&3)*8; LDS offset = c*8 elems (16B/lane)
    const int arow = tid >> 2, acol = (tid & 3) * 8;
    const __bf16* gAh = Ahi + (row0 + arow) * K + acol;
    const __bf16* gAh2 = gAh + (size_t)64 * K;
    const __bf16* gAl = Alo + (row0 + arow) * K + acol;
    const __bf16* gAl2 = gAl + (size_t)64 * K;
    const __bf16* gBh = Bhi + (col0 + arow) * K + acol;   // arow<64 covers B rows
    const __bf16* gBl = Blo + (col0 + arow) * K + acol;
    __bf16* lAh = sAhi + tid * 8;
    __bf16* lAh2 = sAhi + tid * 8 + 2048;
    __bf16* lAl = sAlo + tid * 8;
    __bf16* lAl2 = sAlo + tid * 8 + 2048;
    __bf16* lBh = sBhi + tid * 8;
    __bf16* lBl = sBlo + tid * 8;

    f32x4 acc[4][2] = {};

    for (int k0 = 0; k0 < K; k0 += 32) {
        async_copy16(gAh, lAh);
        async_copy16(gAh2, lAh2);
        async_copy16(gAl, lAl);
        async_copy16(gAl2, lAl2);
        async_copy16(gBh, lBh);
        async_copy16(gBl, lBl);
        gAh += 32; gAh2 += 32; gAl += 32; gAl2 += 32; gBh += 32; gBl += 32;
        __syncthreads();

        bf16x8 a_h[4], a_l[4], b_h[2], b_l[2];
#pragma unroll
        for (int i = 0; i < 4; ++i) {
            a_h[i] = *(const bf16x8*)&sAhi[(wm + i * 16 + qr) * 32 + quad * 8];
            a_l[i] = *(const bf16x8*)&sAlo[(wm + i * 16 + qr) * 32 + quad * 8];
        }
#pragma unroll
        for (int j = 0; j < 2; ++j) {
            b_h[j] = *(const bf16x8*)&sBhi[(wn + j * 16 + qr) * 32 + quad * 8];
            b_l[j] = *(const bf16x8*)&sBlo[(wn + j * 16 + qr) * 32 + quad * 8];
        }
#pragma unroll
        for (int i = 0; i < 4; ++i)
#pragma unroll
            for (int j = 0; j < 2; ++j) {
                acc[i][j] = __builtin_amdgcn_mfma_f32_16x16x32_bf16(a_h[i], b_h[j], acc[i][j], 0, 0, 0);
                acc[i][j] = __builtin_amdgcn_mfma_f32_16x16x32_bf16(a_h[i], b_l[j], acc[i][j], 0, 0, 0);
                acc[i][j] = __builtin_amdgcn_mfma_f32_16x16x32_bf16(a_l[i], b_h[j], acc[i][j], 0, 0, 0);
            }
        __syncthreads();
    }

    // epilogue: C/D layout col=lane&15, row=quad*4+reg
#pragma unroll
    for (int i = 0; i < 4; ++i)
#pragma unroll
        for (int j = 0; j < 2; ++j)
#pragma unroll
            for (int r = 0; r < 4; ++r) {
                size_t idx = (row0 + wm + i * 16 + quad * 4 + r) * N +
                             col0 + wn + j * 16 + qr;
                float x = acc[i][j][r];
                if (OUTMODE == 0) {
                    Cf[idx] = x;
                } else if (OUTMODE == 1) {
                    Chi[idx] = __float2bfloat16(x);
                } else {
                    __bf16 hv = (__bf16)x;
                    Chi[idx] = *(__hip_bfloat16*)&hv;
                    __bf16 lv = (__bf16)(x - (float)hv);
                    Clo[idx] = *(__hip_bfloat16*)&lv;
                }
            }
}

// MFMA flash attention. Block = 64 q-rows x 1 head; 4 waves x 16 rows each.
// All inputs pre-split bf16 (q scaled via Wq). Output: hi/lo planes.
__global__ __launch_bounds__(256) void attn_mfma(const __bf16* __restrict__ qhi_g,
                                                 const __bf16* __restrict__ qlo_g,
                                                 const __bf16* __restrict__ khi_g,
                                                 const __bf16* __restrict__ klo_g,
                                                 const __bf16* __restrict__ vhT,
                                                 const float* __restrict__ scalars,
                                                 __bf16* __restrict__ ohi_g,
                                                 __bf16* __restrict__ olo_g) {
    const int h = blockIdx.y;
    const int q0 = blockIdx.x * 64;
    __shared__ __align__(16) __bf16 Khi[64][136];  // padded: 272B stride
    __shared__ __align__(16) __bf16 Klo[64][136];
    __shared__ __align__(16) __bf16 VT[128][72];   // [head-dim][kpos], 144B stride
    __shared__ __align__(16) __bf16 Ps[64][72];    // [q-row][kpos]

    const int tid = threadIdx.x;
    const int lane = tid & 63;
    const int wave = tid >> 6;
    const int qr = lane & 15;
    const int quad = lane >> 4;

    // ---- Q fragments (rows q0 + wave*16 + qr), already scaled & split
    bf16x8 qfh[4], qfl[4];
    {
        const __bf16* qrh = qhi_g + (size_t)(q0 + wave * 16 + qr) * DMODEL + h * HEADD;
        const __bf16* qrl = qlo_g + (size_t)(q0 + wave * 16 + qr) * DMODEL + h * HEADD;
#pragma unroll
        for (int kc = 0; kc < 4; ++kc) {
            qfh[kc] = *(const bf16x8*)&qrh[kc * 32 + quad * 8];
            qfl[kc] = *(const bf16x8*)&qrl[kc * 32 + quad * 8];
        }
    }

    f32x4 oacc[8] = {};
    float m_r[4], l_r[4];
#pragma unroll
    for (int r = 0; r < 4; ++r) { m_r[r] = 0.f; l_r[r] = 1.f; }  // softmax1 init

    for (int k0 = 0; k0 < S_LEN; k0 += 64) {
        // ---- stage K tile (64 x 128, bf16 hi/lo copies)
#pragma unroll
        for (int i = 0; i < 4; ++i) {
            int idx = tid + i * 256;
            int kp = idx >> 4;
            int c8 = (idx & 15) * 8;
            size_t goff = (size_t)(k0 + kp) * DMODEL + h * HEADD + c8;
            *(bf16x8*)&Khi[kp][c8] = *(const bf16x8*)&khi_g[goff];
            *(bf16x8*)&Klo[kp][c8] = *(const bf16x8*)&klo_g[goff];
        }
        // ---- stage V^T tile (128 dims x 64 kpos, bf16)
#pragma unroll
        for (int i = 0; i < 4; ++i) {
            int idx = tid + i * 256;
            int dm = idx >> 3;
            int c8 = (idx & 7) * 8;
            *(bf16x8*)&VT[dm][c8] =
                *(const bf16x8*)&vhT[(size_t)(h * HEADD + dm) * S_LEN + k0 + c8];
        }
        __syncthreads();

        // ---- S = Q K^T (split 3-term), 4 col-tiles of 16
        f32x4 S[4] = {};
#pragma unroll
        for (int jt = 0; jt < 4; ++jt) {
#pragma unroll
            for (int kc = 0; kc < 4; ++kc) {
                bf16x8 kh8 = *(const bf16x8*)&Khi[jt * 16 + qr][kc * 32 + quad * 8];
                bf16x8 kl8 = *(const bf16x8*)&Klo[jt * 16 + qr][kc * 32 + quad * 8];
                S[jt] = __builtin_amdgcn_mfma_f32_16x16x32_bf16(qfh[kc], kh8, S[jt], 0, 0, 0);
                S[jt] = __builtin_amdgcn_mfma_f32_16x16x32_bf16(qfh[kc], kl8, S[jt], 0, 0, 0);
                S[jt] = __builtin_amdgcn_mfma_f32_16x16x32_bf16(qfl[kc], kh8, S[jt], 0, 0, 0);
            }
        }

        // ---- online softmax1 per row (rows quad*4+r), P -> LDS bf16
#pragma unroll
        for (int r = 0; r < 4; ++r) {
            float mx = fmaxf(fmaxf(S[0][r], S[1][r]), fmaxf(S[2][r], S[3][r]));
#pragma unroll
            for (int m = 1; m < 16; m <<= 1) mx = fmaxf(mx, __shfl_xor(mx, m, 64));
            float m_new = fmaxf(m_r[r], mx);
            float alpha = __expf(m_r[r] - m_new);
            float sum = 0.f;
            int prow = wave * 16 + quad * 4 + r;
#pragma unroll
            for (int jt = 0; jt < 4; ++jt) {
                float e = __expf(S[jt][r] - m_new);
                sum += e;
                Ps[prow][jt * 16 + qr] = (__bf16)e;
            }
#pragma unroll
            for (int m = 1; m < 16; m <<= 1) sum += __shfl_xor(sum, m, 64);
            l_r[r] = l_r[r] * alpha + sum;
            m_r[r] = m_new;
#pragma unroll
            for (int nt = 0; nt < 8; ++nt) oacc[nt][r] *= alpha;
        }
        __syncthreads();

        // ---- O += P @ V
#pragma unroll
        for (int kc = 0; kc < 2; ++kc) {
            bf16x8 pf = *(const bf16x8*)&Ps[wave * 16 + qr][kc * 32 + quad * 8];
#pragma unroll
            for (int nt = 0; nt < 8; ++nt) {
                bf16x8 vf = *(const bf16x8*)&VT[nt * 16 + qr][kc * 32 + quad * 8];
                oacc[nt] = __builtin_amdgcn_mfma_f32_16x16x32_bf16(pf, vf, oacc[nt], 0, 0, 0);
            }
        }
        __syncthreads();
    }

    const float sh = scalars[h];
#pragma unroll
    for (int r = 0; r < 4; ++r) {
        float wm = sh / l_r[r];
        size_t rowoff = (size_t)(q0 + wave * 16 + quad * 4 + r) * DMODEL + h * HEADD;
#pragma unroll
        for (int nt = 0; nt < 8; ++nt) {
            float x = oacc[nt][r] * wm;
            __bf16 hv = (__bf16)x;
            ohi_g[rowoff + nt * 16 + qr] = hv;
            olo_g[rowoff + nt * 16 + qr] = (__bf16)(x - (float)hv);
        }
    }
}

extern "C" void kernel_launch(void* const* d_in, const int* in_sizes, int n_in,
                              void* d_out, int out_size, void* d_ws, size_t ws_size,
                              hipStream_t stream) {
    const float* query   = (const float*)d_in[0];
    const float* key_    = (const float*)d_in[1];
    const float* value   = (const float*)d_in[2];
    const float* Wq      = (const float*)d_in[3];
    const float* Wk      = (const float*)d_in[4];
    const float* Wv      = (const float*)d_in[5];
    const float* Wo      = (const float*)d_in[6];
    const float* scalars = (const float*)d_in[7];
    float* out = (float*)d_out;

    const size_t PL = (size_t)S_LEN * DMODEL;  // elements per plane (8 MB bf16)
    __bf16* P = (__bf16*)d_ws;
    __bf16* pa_hi = P;                // slot A: activation/weight hi
    __bf16* pa_lo = P + PL;
    __bf16* pb_hi = P + 2 * PL;       // slot B
    __bf16* pb_lo = P + 3 * PL;
    __bf16* qh_hi = P + 4 * PL;       // Q proj out, later attn out
    __bf16* qh_lo = P + 5 * PL;
    __bf16* kh_hi = P + 6 * PL;
    __bf16* kh_lo = P + 7 * PL;
    __bf16* vhT   = P + 8 * PL;       // total 72 MB

    const float scale = 0.08838834764831844f;  // 1/sqrt(128)
    dim3 cg(2048 * 2048 / 4 / 256, 2), cb(256);
    dim3 gg(DMODEL / 64, S_LEN / 128), gb(256);

#define CONV(sA, scA, sB, scB)                                                   \
    conv2<<<cg, cb, 0, stream>>>(sA, (__hip_bfloat16*)pa_hi, (__hip_bfloat16*)pa_lo, scA, \
                                 sB, (__hip_bfloat16*)pb_hi, (__hip_bfloat16*)pb_lo, scB)

    CONV(query, 1.0f, Wq, scale);
    gemm_nt3<2><<<gg, gb, 0, stream>>>(pa_hi, pa_lo, pb_hi, pb_lo,
                                       nullptr, (__hip_bfloat16*)qh_hi, (__hip_bfloat16*)qh_lo);
    CONV(key_, 1.0f, Wk, 1.0f);
    gemm_nt3<2><<<gg, gb, 0, stream>>>(pa_hi, pa_lo, pb_hi, pb_lo,
                                       nullptr, (__hip_bfloat16*)kh_hi, (__hip_bfloat16*)kh_lo);
    // vhT = (value @ Wv^T)^T = Wv @ value^T  (A = Wv, B = value)
    CONV(Wv, 1.0f, value, 1.0f);
    gemm_nt3<1><<<gg, gb, 0, stream>>>(pa_hi, pa_lo, pb_hi, pb_lo,
                                       nullptr, (__hip_bfloat16*)vhT, nullptr);

    // attention: reads qh planes (own rows, at start), writes same region
    attn_mfma<<<dim3(S_LEN / 64, NHEAD), 256, 0, stream>>>(
        qh_hi, qh_lo, kh_hi, kh_lo, vhT, scalars, qh_hi, qh_lo);

    // out = attn @ Wo^T
    conv2<<<dim3(2048 * 2048 / 4 / 256, 1), cb, 0, stream>>>(
        Wo, (__hip_bfloat16*)pb_hi, (__hip_bfloat16*)pb_lo, 1.0f,
        Wo, (__hip_bfloat16*)pb_hi, (__hip_bfloat16*)pb_lo, 1.0f);
    gemm_nt3<0><<<gg, gb, 0, stream>>>(qh_hi, qh_lo, pb_hi, pb_lo,
                                       out, nullptr, nullptr);
#undef CONV
}

// Round 6
// 566.053 us; speedup vs baseline: 3.7402x; 1.0142x over previous
//
#include <hip/hip_runtime.h>
#include <hip/hip_bf16.h>

// Problem: S=2048, D_MODEL=2048, H=16, HD=128
// out = softmax1((q@Wq^T)(k@Wk^T)^T / sqrt(HD)) @ (v@Wv^T) * scalars @ Wo^T
//
// Round 6:
//  - gemm_nt3: 3-term split GEMM, tile 128x64, 128 threads = 2 waves,
//    wave-tile 64x64 (16 LDS reads : 48 MFMAs per K-step — near-balanced),
//    Q+K projections fused via gridDim.z=2 (1024 blocks → 4+ blocks/CU).
//  - conv2: fp32 -> (hi,lo) bf16 planes (scale folded into Wq).
//  - attn_mfma: unchanged from round 5 (142 us; next round's target).

#define S_LEN 2048
#define DMODEL 2048
#define NHEAD 16
#define HEADD 128

typedef __bf16 bf16x8 __attribute__((ext_vector_type(8)));
typedef __bf16 bf16x4 __attribute__((ext_vector_type(4)));
typedef float f32x4 __attribute__((ext_vector_type(4)));

__device__ inline void async_copy16(const __bf16* g, __bf16* l) {
    __builtin_amdgcn_global_load_lds(
        (const __attribute__((address_space(1))) unsigned int*)g,
        (__attribute__((address_space(3))) unsigned int*)l, 16, 0, 0);
}

// ---- fp32 -> hi/lo bf16 split conversion, up to 2 matrices per launch ----
__global__ __launch_bounds__(256) void conv2(const float* __restrict__ s0,
                                             __hip_bfloat16* __restrict__ h0,
                                             __hip_bfloat16* __restrict__ l0,
                                             float sc0,
                                             const float* __restrict__ s1,
                                             __hip_bfloat16* __restrict__ h1,
                                             __hip_bfloat16* __restrict__ l1,
                                             float sc1) {
    const float* s = blockIdx.y ? s1 : s0;
    __hip_bfloat16* ph = blockIdx.y ? h1 : h0;
    __hip_bfloat16* pl = blockIdx.y ? l1 : l0;
    const float sc = blockIdx.y ? sc1 : sc0;
    size_t i4 = (size_t)blockIdx.x * 256 + threadIdx.x;  // float4 index
    float4 v = *(const float4*)&s[i4 * 4];
    float x0 = v.x * sc, x1 = v.y * sc, x2 = v.z * sc, x3 = v.w * sc;
    bf16x4 hv, lv;
    __bf16 a0 = (__bf16)x0, a1 = (__bf16)x1, a2 = (__bf16)x2, a3 = (__bf16)x3;
    hv[0] = a0; hv[1] = a1; hv[2] = a2; hv[3] = a3;
    lv[0] = (__bf16)(x0 - (float)a0); lv[1] = (__bf16)(x1 - (float)a1);
    lv[2] = (__bf16)(x2 - (float)a2); lv[3] = (__bf16)(x3 - (float)a3);
    *(bf16x4*)&ph[i4 * 4] = hv;
    *(bf16x4*)&pl[i4 * 4] = lv;
}

struct GArgs {
    const __bf16 *Ah, *Al, *Bh, *Bl;
    float* Cf;
    __bf16 *Ch, *Cl;
};

// ---- C = A @ B^T, pre-split hi/lo planes. Tile 128(M) x 64(N), BK=32.
// 128 threads = 2 waves; wave w owns rows [w*64, w*64+64) x all 64 cols.
// OUTMODE: 0 = fp32, 1 = bf16, 2 = hi/lo bf16 planes. blockIdx.z picks g0/g1.
template <int OUTMODE>
__global__ __launch_bounds__(128, 3) void gemm_nt3(GArgs g0, GArgs g1) {
    constexpr int K = DMODEL, N = DMODEL;
    const GArgs g = blockIdx.z ? g1 : g0;
    __shared__ __bf16 sAh[128 * 32], sAl[128 * 32];
    __shared__ __bf16 sBh[64 * 32], sBl[64 * 32];

    const int tid = threadIdx.x;   // 0..127
    const int lane = tid & 63;
    const int wave = tid >> 6;     // 0..1
    const int qr = lane & 15;
    const int quad = lane >> 4;
    const size_t row0 = (size_t)blockIdx.y * 128;
    const size_t col0 = (size_t)blockIdx.x * 64;

    // staging: chunk (c*128+tid) -> row = c*32 + tid>>2, k8 = (tid&3)*8;
    // LDS offset = chunk*16B (lane-contiguous per global_load_lds constraint)
    const int srow = tid >> 2;
    const int k8 = (tid & 3) * 8;
    const __bf16* gAh = g.Ah + (row0 + srow) * K + k8;
    const __bf16* gAl = g.Al + (row0 + srow) * K + k8;
    const __bf16* gBh = g.Bh + (col0 + srow) * K + k8;
    const __bf16* gBl = g.Bl + (col0 + srow) * K + k8;

    f32x4 acc[4][4] = {};

    for (int k0 = 0; k0 < K; k0 += 32) {
#pragma unroll
        for (int c = 0; c < 4; ++c) {
            async_copy16(gAh + (size_t)c * 32 * K, sAh + c * 1024 + tid * 8);
            async_copy16(gAl + (size_t)c * 32 * K, sAl + c * 1024 + tid * 8);
        }
#pragma unroll
        for (int c = 0; c < 2; ++c) {
            async_copy16(gBh + (size_t)c * 32 * K, sBh + c * 1024 + tid * 8);
            async_copy16(gBl + (size_t)c * 32 * K, sBl + c * 1024 + tid * 8);
        }
        gAh += 32; gAl += 32; gBh += 32; gBl += 32;
        __syncthreads();

        bf16x8 a_h[4], a_l[4], b_h[4], b_l[4];
#pragma unroll
        for (int i = 0; i < 4; ++i) {
            a_h[i] = *(const bf16x8*)&sAh[(wave * 64 + i * 16 + qr) * 32 + quad * 8];
            a_l[i] = *(const bf16x8*)&sAl[(wave * 64 + i * 16 + qr) * 32 + quad * 8];
        }
#pragma unroll
        for (int j = 0; j < 4; ++j) {
            b_h[j] = *(const bf16x8*)&sBh[(j * 16 + qr) * 32 + quad * 8];
            b_l[j] = *(const bf16x8*)&sBl[(j * 16 + qr) * 32 + quad * 8];
        }
#pragma unroll
        for (int i = 0; i < 4; ++i)
#pragma unroll
            for (int j = 0; j < 4; ++j) {
                acc[i][j] = __builtin_amdgcn_mfma_f32_16x16x32_bf16(a_h[i], b_h[j], acc[i][j], 0, 0, 0);
                acc[i][j] = __builtin_amdgcn_mfma_f32_16x16x32_bf16(a_h[i], b_l[j], acc[i][j], 0, 0, 0);
                acc[i][j] = __builtin_amdgcn_mfma_f32_16x16x32_bf16(a_l[i], b_h[j], acc[i][j], 0, 0, 0);
            }
        __syncthreads();
    }

    // epilogue: C/D layout col=lane&15, row=quad*4+reg
#pragma unroll
    for (int i = 0; i < 4; ++i)
#pragma unroll
        for (int j = 0; j < 4; ++j)
#pragma unroll
            for (int r = 0; r < 4; ++r) {
                size_t idx = (row0 + wave * 64 + i * 16 + quad * 4 + r) * N +
                             col0 + j * 16 + qr;
                float x = acc[i][j][r];
                if (OUTMODE == 0) {
                    g.Cf[idx] = x;
                } else if (OUTMODE == 1) {
                    g.Ch[idx] = (__bf16)x;
                } else {
                    __bf16 hv = (__bf16)x;
                    g.Ch[idx] = hv;
                    g.Cl[idx] = (__bf16)(x - (float)hv);
                }
            }
}

// MFMA flash attention. Block = 64 q-rows x 1 head; 4 waves x 16 rows each.
__global__ __launch_bounds__(256) void attn_mfma(const __bf16* __restrict__ qhi_g,
                                                 const __bf16* __restrict__ qlo_g,
                                                 const __bf16* __restrict__ khi_g,
                                                 const __bf16* __restrict__ klo_g,
                                                 const __bf16* __restrict__ vhT,
                                                 const float* __restrict__ scalars,
                                                 __bf16* __restrict__ ohi_g,
                                                 __bf16* __restrict__ olo_g) {
    const int h = blockIdx.y;
    const int q0 = blockIdx.x * 64;
    __shared__ __align__(16) __bf16 Khi[64][136];  // padded: 272B stride
    __shared__ __align__(16) __bf16 Klo[64][136];
    __shared__ __align__(16) __bf16 VT[128][72];   // [head-dim][kpos], 144B stride
    __shared__ __align__(16) __bf16 Ps[64][72];    // [q-row][kpos]

    const int tid = threadIdx.x;
    const int lane = tid & 63;
    const int wave = tid >> 6;
    const int qr = lane & 15;
    const int quad = lane >> 4;

    bf16x8 qfh[4], qfl[4];
    {
        const __bf16* qrh = qhi_g + (size_t)(q0 + wave * 16 + qr) * DMODEL + h * HEADD;
        const __bf16* qrl = qlo_g + (size_t)(q0 + wave * 16 + qr) * DMODEL + h * HEADD;
#pragma unroll
        for (int kc = 0; kc < 4; ++kc) {
            qfh[kc] = *(const bf16x8*)&qrh[kc * 32 + quad * 8];
            qfl[kc] = *(const bf16x8*)&qrl[kc * 32 + quad * 8];
        }
    }

    f32x4 oacc[8] = {};
    float m_r[4], l_r[4];
#pragma unroll
    for (int r = 0; r < 4; ++r) { m_r[r] = 0.f; l_r[r] = 1.f; }  // softmax1 init

    for (int k0 = 0; k0 < S_LEN; k0 += 64) {
#pragma unroll
        for (int i = 0; i < 4; ++i) {
            int idx = tid + i * 256;
            int kp = idx >> 4;
            int c8 = (idx & 15) * 8;
            size_t goff = (size_t)(k0 + kp) * DMODEL + h * HEADD + c8;
            *(bf16x8*)&Khi[kp][c8] = *(const bf16x8*)&khi_g[goff];
            *(bf16x8*)&Klo[kp][c8] = *(const bf16x8*)&klo_g[goff];
        }
#pragma unroll
        for (int i = 0; i < 4; ++i) {
            int idx = tid + i * 256;
            int dm = idx >> 3;
            int c8 = (idx & 7) * 8;
            *(bf16x8*)&VT[dm][c8] =
                *(const bf16x8*)&vhT[(size_t)(h * HEADD + dm) * S_LEN + k0 + c8];
        }
        __syncthreads();

        f32x4 S[4] = {};
#pragma unroll
        for (int jt = 0; jt < 4; ++jt) {
#pragma unroll
            for (int kc = 0; kc < 4; ++kc) {
                bf16x8 kh8 = *(const bf16x8*)&Khi[jt * 16 + qr][kc * 32 + quad * 8];
                bf16x8 kl8 = *(const bf16x8*)&Klo[jt * 16 + qr][kc * 32 + quad * 8];
                S[jt] = __builtin_amdgcn_mfma_f32_16x16x32_bf16(qfh[kc], kh8, S[jt], 0, 0, 0);
                S[jt] = __builtin_amdgcn_mfma_f32_16x16x32_bf16(qfh[kc], kl8, S[jt], 0, 0, 0);
                S[jt] = __builtin_amdgcn_mfma_f32_16x16x32_bf16(qfl[kc], kh8, S[jt], 0, 0, 0);
            }
        }

#pragma unroll
        for (int r = 0; r < 4; ++r) {
            float mx = fmaxf(fmaxf(S[0][r], S[1][r]), fmaxf(S[2][r], S[3][r]));
#pragma unroll
            for (int m = 1; m < 16; m <<= 1) mx = fmaxf(mx, __shfl_xor(mx, m, 64));
            float m_new = fmaxf(m_r[r], mx);
            float alpha = __expf(m_r[r] - m_new);
            float sum = 0.f;
            int prow = wave * 16 + quad * 4 + r;
#pragma unroll
            for (int jt = 0; jt < 4; ++jt) {
                float e = __expf(S[jt][r] - m_new);
                sum += e;
                Ps[prow][jt * 16 + qr] = (__bf16)e;
            }
#pragma unroll
            for (int m = 1; m < 16; m <<= 1) sum += __shfl_xor(sum, m, 64);
            l_r[r] = l_r[r] * alpha + sum;
            m_r[r] = m_new;
#pragma unroll
            for (int nt = 0; nt < 8; ++nt) oacc[nt][r] *= alpha;
        }
        __syncthreads();

#pragma unroll
        for (int kc = 0; kc < 2; ++kc) {
            bf16x8 pf = *(const bf16x8*)&Ps[wave * 16 + qr][kc * 32 + quad * 8];
#pragma unroll
            for (int nt = 0; nt < 8; ++nt) {
                bf16x8 vf = *(const bf16x8*)&VT[nt * 16 + qr][kc * 32 + quad * 8];
                oacc[nt] = __builtin_amdgcn_mfma_f32_16x16x32_bf16(pf, vf, oacc[nt], 0, 0, 0);
            }
        }
        __syncthreads();
    }

    const float sh = scalars[h];
#pragma unroll
    for (int r = 0; r < 4; ++r) {
        float wm = sh / l_r[r];
        size_t rowoff = (size_t)(q0 + wave * 16 + quad * 4 + r) * DMODEL + h * HEADD;
#pragma unroll
        for (int nt = 0; nt < 8; ++nt) {
            float x = oacc[nt][r] * wm;
            __bf16 hv = (__bf16)x;
            ohi_g[rowoff + nt * 16 + qr] = hv;
            olo_g[rowoff + nt * 16 + qr] = (__bf16)(x - (float)hv);
        }
    }
}

extern "C" void kernel_launch(void* const* d_in, const int* in_sizes, int n_in,
                              void* d_out, int out_size, void* d_ws, size_t ws_size,
                              hipStream_t stream) {
    const float* query   = (const float*)d_in[0];
    const float* key_    = (const float*)d_in[1];
    const float* value   = (const float*)d_in[2];
    const float* Wq      = (const float*)d_in[3];
    const float* Wk      = (const float*)d_in[4];
    const float* Wv      = (const float*)d_in[5];
    const float* Wo      = (const float*)d_in[6];
    const float* scalars = (const float*)d_in[7];
    float* out = (float*)d_out;

    const size_t PL = (size_t)S_LEN * DMODEL;  // elements per 8 MB plane
    __bf16* p[12];
    for (int i = 0; i < 12; ++i) p[i] = (__bf16*)d_ws + i * PL;  // 96 MB total
    // p0..p3: input slot A (act hi/lo, wt hi/lo) — reused
    // p4..p7: input slot B (also later: p4 = vhT)
    // p8,p9: qh hi/lo (later attn-out hi/lo); p10,p11: kh hi/lo

    const float scale = 0.08838834764831844f;  // 1/sqrt(128)
    dim3 cg(2048 * 2048 / 4 / 256, 2), cb(256);
    dim3 gg(DMODEL / 64, S_LEN / 128, 1), gb(128);
    dim3 gg2(DMODEL / 64, S_LEN / 128, 2);

#define BH(x) (__hip_bfloat16*)(x)
    conv2<<<cg, cb, 0, stream>>>(query, BH(p[0]), BH(p[1]), 1.0f,
                                 Wq, BH(p[2]), BH(p[3]), scale);
    conv2<<<cg, cb, 0, stream>>>(key_, BH(p[4]), BH(p[5]), 1.0f,
                                 Wk, BH(p[6]), BH(p[7]), 1.0f);
    {
        GArgs gq = {p[0], p[1], p[2], p[3], nullptr, p[8], p[9]};
        GArgs gk = {p[4], p[5], p[6], p[7], nullptr, p[10], p[11]};
        gemm_nt3<2><<<gg2, gb, 0, stream>>>(gq, gk);
    }
    conv2<<<cg, cb, 0, stream>>>(Wv, BH(p[0]), BH(p[1]), 1.0f,
                                 value, BH(p[2]), BH(p[3]), 1.0f);
    {
        // vhT = (value @ Wv^T)^T = Wv @ value^T  (A = Wv, B = value)
        GArgs gv = {p[0], p[1], p[2], p[3], nullptr, p[4], nullptr};
        gemm_nt3<1><<<gg, gb, 0, stream>>>(gv, gv);
    }

    attn_mfma<<<dim3(S_LEN / 64, NHEAD), 256, 0, stream>>>(
        p[8], p[9], p[10], p[11], p[4], scalars, p[8], p[9]);

    conv2<<<dim3(2048 * 2048 / 4 / 256, 1), cb, 0, stream>>>(
        Wo, BH(p[0]), BH(p[1]), 1.0f, Wo, BH(p[0]), BH(p[1]), 1.0f);
    {
        GArgs go = {p[8], p[9], p[0], p[1], out, nullptr, nullptr};
        gemm_nt3<0><<<gg, gb, 0, stream>>>(go, go);
    }
#undef BH
}